// Round 2
// baseline (537.816 us; speedup 1.0000x reference)
//
#include <hip/hip_runtime.h>
#include <hip/hip_bf16.h>

typedef unsigned short u16;
typedef unsigned int u32;
typedef short s16x8 __attribute__((ext_vector_type(8)));
typedef float f32x4 __attribute__((ext_vector_type(4)));
typedef float f32x2 __attribute__((ext_vector_type(2)));
typedef float f32x16 __attribute__((ext_vector_type(16)));
typedef u32 u32x2 __attribute__((ext_vector_type(2)));

__device__ __forceinline__ float bf2f(u16 u) {
    union { u32 i; float f; } v; v.i = ((u32)u) << 16; return v.f;
}
__device__ __forceinline__ u16 f2bf(float f) {
    union { float f; u32 i; } v; v.f = f;
    u32 i = v.i;
    u32 r = (i + 0x7FFFu + ((i >> 16) & 1u)) >> 16;   // round-to-nearest-even
    return (u16)r;
}
__device__ __forceinline__ u32 cvtpk_bf16(float lo, float hi) {
    u32 r;
    asm("v_cvt_pk_bf16_f32 %0, %1, %2" : "=v"(r) : "v"(lo), "v"(hi));
    return r;
}
__device__ __forceinline__ float bitf(u32 x) {
    union { u32 i; float f; } v; v.i = x; return v.f;
}

// async global->LDS, 16 B per lane: dest = lds_base + lane*16 (wave-uniform base)
__device__ __forceinline__ void gl2lds16(const u16* g, u16* l) {
    __builtin_amdgcn_global_load_lds(
        (const __attribute__((address_space(1))) u32*)g,
        (__attribute__((address_space(3))) u32*)l, 16, 0, 0);
}

// ---------------------------------------------------------------------------
// Convert f32 -> bf16, 2 elements/thread.
// ---------------------------------------------------------------------------
__global__ __launch_bounds__(256) void cvt_f32_bf16(
    const float* __restrict__ in, u16* __restrict__ out, long long n2)
{
    long long i = (long long)blockIdx.x * 256 + threadIdx.x;
    if (i < n2) {
        f32x2 v = *(const f32x2*)(in + i * 2);
        u32 p = (u32)f2bf(v[0]) | ((u32)f2bf(v[1]) << 16);
        *(u32*)(out + i * 2) = p;
    }
}

// ---------------------------------------------------------------------------
// Transpose + convert: f32 in[R][C] -> bf16 out[C][R].  R,C multiples of 32.
// ---------------------------------------------------------------------------
__global__ __launch_bounds__(256) void transpose_f32_bf16(
    const float* __restrict__ in, u16* __restrict__ out, int R, int C)
{
    __shared__ u16 t[32][33];
    int tx = threadIdx.x & 31, ty = threadIdx.x >> 5;
    int c0 = blockIdx.x * 32, r0 = blockIdx.y * 32;
    #pragma unroll
    for (int i = 0; i < 32; i += 8)
        t[ty + i][tx] = f2bf(in[(size_t)(r0 + ty + i) * C + c0 + tx]);
    __syncthreads();
    #pragma unroll
    for (int i = 0; i < 32; i += 8)
        out[(size_t)(c0 + ty + i) * R + r0 + tx] = t[tx][ty + i];
}

// ---------------------------------------------------------------------------
// V transpose: kvup V-half -> vt[b][h][v][s]  (bf16 -> bf16, 32x32 LDS tiles)
// grid = (64 s-tiles, 4 v-tiles, 32 bh), block = 256
// ---------------------------------------------------------------------------
__global__ __launch_bounds__(256) void transpose_v(
    const u16* __restrict__ kvup, u16* __restrict__ vt)
{
    __shared__ u16 t[32][33];
    int tx = threadIdx.x & 31, ty = threadIdx.x >> 5;
    int s0 = blockIdx.x * 32, v0 = blockIdx.y * 32;
    int b = blockIdx.z >> 4, h = blockIdx.z & 15;
    #pragma unroll
    for (int i = 0; i < 32; i += 8)
        t[ty + i][tx] = kvup[(size_t)(b * 2048 + s0 + ty + i) * 4096 + h * 256 + 128 + v0 + tx];
    __syncthreads();
    #pragma unroll
    for (int i = 0; i < 32; i += 8)
        vt[((size_t)(b * 16 + h) * 128 + v0 + ty + i) * 2048 + s0 + tx] = t[tx][ty + i];
}

// ---------------------------------------------------------------------------
// GEMM 64x64 tile (kept for kv_down: N=576 not /128).
// ---------------------------------------------------------------------------
__global__ __launch_bounds__(256) void gemm_bf16(
    const u16* __restrict__ A, const u16* __restrict__ Bt, u16* __restrict__ C,
    int M, int N, int K)
{
    __shared__ u16 As[64][40];
    __shared__ u16 Bs[64][40];

    const int tid  = threadIdx.x;
    const int wave = tid >> 6, lane = tid & 63;
    const int quad = lane >> 4, l16 = lane & 15;
    const int m0 = blockIdx.y * 64, n0 = blockIdx.x * 64;
    const int wm = (wave >> 1) * 32, wn = (wave & 1) * 32;

    const int srow = tid >> 2;
    const int koff = (tid & 3) * 8;

    f32x4 acc00 = {0.f,0.f,0.f,0.f};
    f32x4 acc01 = {0.f,0.f,0.f,0.f};
    f32x4 acc10 = {0.f,0.f,0.f,0.f};
    f32x4 acc11 = {0.f,0.f,0.f,0.f};

    for (int k0 = 0; k0 < K; k0 += 32) {
        *(s16x8*)&As[srow][koff] = *(const s16x8*)&A[(size_t)(m0 + srow) * K + k0 + koff];
        *(s16x8*)&Bs[srow][koff] = *(const s16x8*)&Bt[(size_t)(n0 + srow) * K + k0 + koff];
        __syncthreads();
        s16x8 a0 = *(const s16x8*)&As[wm + l16][quad * 8];
        s16x8 a1 = *(const s16x8*)&As[wm + 16 + l16][quad * 8];
        s16x8 b0 = *(const s16x8*)&Bs[wn + l16][quad * 8];
        s16x8 b1 = *(const s16x8*)&Bs[wn + 16 + l16][quad * 8];
        acc00 = __builtin_amdgcn_mfma_f32_16x16x32_bf16(a0, b0, acc00, 0, 0, 0);
        acc01 = __builtin_amdgcn_mfma_f32_16x16x32_bf16(a0, b1, acc01, 0, 0, 0);
        acc10 = __builtin_amdgcn_mfma_f32_16x16x32_bf16(a1, b0, acc10, 0, 0, 0);
        acc11 = __builtin_amdgcn_mfma_f32_16x16x32_bf16(a1, b1, acc11, 0, 0, 0);
        __syncthreads();
    }

    #pragma unroll
    for (int r = 0; r < 4; ++r) {
        int row0 = m0 + wm + quad * 4 + r;
        int col0 = n0 + wn + l16;
        C[(size_t)row0 * N + col0]             = f2bf(acc00[r]);
        C[(size_t)row0 * N + col0 + 16]        = f2bf(acc01[r]);
        C[(size_t)(row0 + 16) * N + col0]      = f2bf(acc10[r]);
        C[(size_t)(row0 + 16) * N + col0 + 16] = f2bf(acc11[r]);
    }
}

// ---------------------------------------------------------------------------
// GEMM 128x128 tile (m97 structure): 4 waves, each 64x64 via 4x4 of 16x16;
// BK=32; global_load_lds width-16 staging into unpadded row-major LDS.
// ---------------------------------------------------------------------------
template <typename OUT>
__global__ __launch_bounds__(256) void gemm128(
    const u16* __restrict__ A, const u16* __restrict__ Bt, OUT* __restrict__ C,
    int M, int N, int K)
{
    __shared__ u16 As[128 * 32];
    __shared__ u16 Bs[128 * 32];

    const int tid  = threadIdx.x;
    const int wave = tid >> 6, lane = tid & 63;
    const int quad = lane >> 4, l16 = lane & 15;
    const int m0 = blockIdx.y * 128, n0 = blockIdx.x * 128;
    const int wm = (wave >> 1) * 64, wn = (wave & 1) * 64;

    const int srow = lane >> 2, soct = (lane & 3) * 8;

    f32x4 acc[4][4];
    #pragma unroll
    for (int i = 0; i < 4; ++i)
        #pragma unroll
        for (int j = 0; j < 4; ++j) acc[i][j] = (f32x4){0.f,0.f,0.f,0.f};

    for (int k0 = 0; k0 < K; k0 += 32) {
        #pragma unroll
        for (int op = 0; op < 2; ++op) {
            int g = wave * 2 + op;
            gl2lds16(&A[(size_t)(m0 + g * 16 + srow) * K + k0 + soct], &As[g * 512]);
            gl2lds16(&Bt[(size_t)(n0 + g * 16 + srow) * K + k0 + soct], &Bs[g * 512]);
        }
        __syncthreads();
        s16x8 af[4], bf[4];
        #pragma unroll
        for (int i = 0; i < 4; ++i) {
            af[i] = *(const s16x8*)&As[(wm + i * 16 + l16) * 32 + quad * 8];
            bf[i] = *(const s16x8*)&Bs[(wn + i * 16 + l16) * 32 + quad * 8];
        }
        #pragma unroll
        for (int i = 0; i < 4; ++i)
            #pragma unroll
            for (int j = 0; j < 4; ++j)
                acc[i][j] = __builtin_amdgcn_mfma_f32_16x16x32_bf16(af[i], bf[j], acc[i][j], 0, 0, 0);
        __syncthreads();
    }

    #pragma unroll
    for (int i = 0; i < 4; ++i) {
        #pragma unroll
        for (int j = 0; j < 4; ++j) {
            #pragma unroll
            for (int r = 0; r < 4; ++r) {
                int row = m0 + wm + i * 16 + quad * 4 + r;
                int col = n0 + wn + j * 16 + l16;
                if constexpr (sizeof(OUT) == 2)
                    C[(size_t)row * N + col] = f2bf(acc[i][j][r]);
                else
                    C[(size_t)row * N + col] = acc[i][j][r];
            }
        }
    }
}

// ---------------------------------------------------------------------------
// RMSNorm rows: out = x * rsqrt(mean(x^2)+eps) * w  (x bf16, w f32, out bf16)
// ---------------------------------------------------------------------------
__global__ __launch_bounds__(256) void rmsnorm_kernel(
    const u16* __restrict__ in, const float* __restrict__ w, u16* __restrict__ out,
    int len, int istride, int ostride)
{
    const int row = blockIdx.x, tid = threadIdx.x;
    const u16* x = in + (size_t)row * istride;
    float ss = 0.f;
    for (int i = tid; i < len; i += 256) { float v = bf2f(x[i]); ss += v * v; }
    #pragma unroll
    for (int off = 32; off >= 1; off >>= 1) ss += __shfl_xor(ss, off, 64);
    __shared__ float wsum[4];
    if ((tid & 63) == 0) wsum[tid >> 6] = ss;
    __syncthreads();
    float tot = wsum[0] + wsum[1] + wsum[2] + wsum[3];
    float inv = 1.0f / sqrtf(tot / (float)len + 1e-6f);
    for (int i = tid; i < len; i += 256) {
        float v = bf2f(x[i]);
        out[(size_t)row * ostride + i] = f2bf(v * inv * w[i]);
    }
}

// ---------------------------------------------------------------------------
// RoPE: q rope halves (16 heads, in-place) + k_rope -> krot. cos/sin f32.
// ---------------------------------------------------------------------------
__global__ __launch_bounds__(256) void rope_kernel(
    u16* __restrict__ qb, const u16* __restrict__ kvb, u16* __restrict__ krot,
    const float* __restrict__ cosb, const float* __restrict__ sinb)
{
    const int row = blockIdx.x;
    const int s = row & 2047;
    const int lane = threadIdx.x & 63, wave = threadIdx.x >> 6;
    const float c  = cosb[s * 64 + lane];
    const float sn = sinb[s * 64 + lane];
    for (int seg = wave; seg < 17; seg += 4) {
        const u16* pin; u16* pout;
        if (seg < 16) { pout = qb + (size_t)row * 3072 + seg * 192 + 128; pin = pout; }
        else          { pin = kvb + (size_t)row * 576 + 512; pout = krot + (size_t)row * 64; }
        float x  = bf2f(pin[lane]);
        float xp = bf2f(pin[lane ^ 32]);
        float rot = (lane < 32) ? -xp : xp;
        pout[lane] = f2bf(x * c + rot * sn);
    }
}

// ---------------------------------------------------------------------------
// MFMA flash attention v5: 32x32x16 swapped-operand structure (m214-style).
//  * QK^T computed as S^T = mfma(K, Q^T): each lane owns one q-row (q=lane&31,
//    lanes l/l+32 split the k-halves). Row max/sum = ONE shfl_xor(32).
//  * P stays in registers: cvt_pk_bf16 pairs + symmetric lane^32 exchange
//    assemble the PV B-fragment directly. No Ps LDS, no scalar ds_writes.
//  * PV computed as O^T = mfma(V^T, P^T); V^T fragments read from the
//    DMA-staged XOR-swizzled Vd (unchanged from v4).
//  * l = sum of the SAME bf16-rounded P values (unpacked from cvt_pk words),
//    numerically consistent with the bf16 PV numerator.
//  * K tile: register prefetch double-buffer (unchanged from v4).
// LDS 57 KB -> 2 blocks/CU; grid = (16, 16, 2).
// ---------------------------------------------------------------------------
__global__ __launch_bounds__(256, 2) void attn_mfma5(
    const u16* __restrict__ qb,     // [4096][3072]  (rope applied)
    const u16* __restrict__ kvup,   // [4096][4096]  (per head: 128 nope | 128 v)
    const u16* __restrict__ krot,   // [4096][64]
    const u16* __restrict__ vt,     // [2][16][128][2048]  V transposed
    const float* __restrict__ mask, // [2][2048]
    u16* __restrict__ attnb)        // [4096][2048]
{
    __shared__ u16 Ks[64 * 200];    // K tile, stride 200 u16 (400 B)
    __shared__ u16 Vd[2][128 * 64]; // V tile double buffer, linear + XOR swizzle

    const int tid  = threadIdx.x;
    const int wave = tid >> 6, lane = tid & 63;
    const int l31  = lane & 31;
    const int hi   = lane >> 5;         // k-half / v-half selector
    const int qt = blockIdx.x, h = blockIdx.y, b = blockIdx.z;
    const int row0 = b * 2048 + qt * 128;
    const int qrow = row0 + wave * 32 + l31;   // this lane's q-row
    const float scale2 = 0.10411610f;          // (1/sqrt(192)) * log2(e)
    const float l2e    = 1.4426950408889634f;

    // Q fragments (B-operand of swapped QK^T): lane holds Q[qrow][d-chunk]
    s16x8 qf[12];
    #pragma unroll
    for (int kc = 0; kc < 12; ++kc)
        qf[kc] = *(const s16x8*)&qb[(size_t)qrow * 3072 + h * 192 + kc * 16 + hi * 8];

    // ---- K staging descriptors (6 x b128 per thread) ----
    const u16* kp[6]; int offk[6], stepk[6];
    #pragma unroll
    for (int i = 0; i < 6; ++i) {
        int idx = tid + i * 256;
        int r = idx / 24, c = (idx % 24) * 8;
        offk[i] = r * 200 + c;
        if (c < 128) { kp[i] = kvup + (size_t)(b * 2048 + r) * 4096 + h * 256 + c; stepk[i] = 64 * 4096; }
        else         { kp[i] = krot + (size_t)(b * 2048 + r) * 64 + (c - 128);     stepk[i] = 64 * 64;   }
    }

    // ---- V staging descriptors (4 x gl2lds per thread, pre-swizzled source) ----
    const u16* vtb = vt + (size_t)(b * 16 + h) * 128 * 2048;
    const u16* pv[4];
    #pragma unroll
    for (int i = 0; i < 4; ++i) {
        int widx = i * 4 + wave;                   // wave-uniform row group
        int r = widx * 8 + (lane >> 3);
        int u = (lane & 7) ^ (lane >> 3);          // source 16B unit, pre-swizzled
        pv[i] = vtb + (size_t)r * 2048 + u * 8;
    }

    // prologue: prefetch tile kt=0 (K into regs, V via DMA into Vd[0])
    s16x8 kreg[6];
    #pragma unroll
    for (int i = 0; i < 6; ++i) { kreg[i] = *(const s16x8*)kp[i]; kp[i] += stepk[i]; }
    #pragma unroll
    for (int i = 0; i < 4; ++i) {
        gl2lds16(pv[i], &Vd[0][(i * 4 + wave) * 512]);
        pv[i] += 64;
    }

    float m_run = -__builtin_inff();
    float l_run = 0.f;
    f32x16 O[4];
    #pragma unroll
    for (int v = 0; v < 4; ++v)
        #pragma unroll
        for (int e = 0; e < 16; ++e) O[v][e] = 0.f;

    for (int kt = 0; kt < 32; ++kt) {
        __syncthreads();   // A: prior iteration's Ks/Vd reads complete
        #pragma unroll
        for (int i = 0; i < 6; ++i) *(s16x8*)&Ks[offk[i]] = kreg[i];
        __syncthreads();   // B: staging visible (drains K ds_writes + V DMA)

        // issue next tile's staging: latency hides under compute
        if (kt < 31) {
            #pragma unroll
            for (int i = 0; i < 6; ++i) { kreg[i] = *(const s16x8*)kp[i]; kp[i] += stepk[i]; }
            #pragma unroll
            for (int i = 0; i < 4; ++i) {
                gl2lds16(pv[i], &Vd[(kt + 1) & 1][(i * 4 + wave) * 512]);
                pv[i] += 64;
            }
        }

        // ---- QK^T (swapped): St[t] = K-tile-t * Q^T,  32x32x16 ----
        f32x16 St[2];
        #pragma unroll
        for (int t = 0; t < 2; ++t)
            #pragma unroll
            for (int e = 0; e < 16; ++e) St[t][e] = 0.f;
        __builtin_amdgcn_s_setprio(1);
        #pragma unroll
        for (int kc = 0; kc < 12; ++kc) {
            s16x8 a0 = *(const s16x8*)&Ks[(l31)      * 200 + kc * 16 + hi * 8];
            s16x8 a1 = *(const s16x8*)&Ks[(32 + l31) * 200 + kc * 16 + hi * 8];
            St[0] = __builtin_amdgcn_mfma_f32_32x32x16_bf16(a0, qf[kc], St[0], 0, 0, 0);
            St[1] = __builtin_amdgcn_mfma_f32_32x32x16_bf16(a1, qf[kc], St[1], 0, 0, 0);
        }
        __builtin_amdgcn_s_setprio(0);

        // scale + mask (log2 domain).  St[t] reg r ↦ k = t*32+(r&3)+8*(r>>2)+4*hi
        #pragma unroll
        for (int t = 0; t < 2; ++t)
            #pragma unroll
            for (int g = 0; g < 4; ++g) {
                f32x4 mk = *(const f32x4*)&mask[b * 2048 + kt * 64 + t * 32 + g * 8 + hi * 4];
                #pragma unroll
                for (int e = 0; e < 4; ++e)
                    St[t][g * 4 + e] = St[t][g * 4 + e] * scale2 + mk[e] * l2e;
            }

        // true row max: own 32 values + one cross-half exchange
        float tm = St[0][0];
        #pragma unroll
        for (int t = 0; t < 2; ++t)
            #pragma unroll
            for (int e = 0; e < 16; ++e) tm = fmaxf(tm, St[t][e]);
        tm = fmaxf(tm, __shfl_xor(tm, 32, 64));
        float mn = fmaxf(m_run, tm);
        float alpha = exp2f(m_run - mn);
        m_run = mn;

        // P = exp2(S - m) -> packed bf16 pairs (register-resident)
        u32 pkw[2][4][2];
        #pragma unroll
        for (int t = 0; t < 2; ++t)
            #pragma unroll
            for (int g = 0; g < 4; ++g) {
                float e0 = exp2f(St[t][g * 4 + 0] - mn);
                float e1 = exp2f(St[t][g * 4 + 1] - mn);
                float e2 = exp2f(St[t][g * 4 + 2] - mn);
                float e3 = exp2f(St[t][g * 4 + 3] - mn);
                pkw[t][g][0] = cvtpk_bf16(e0, e1);
                pkw[t][g][1] = cvtpk_bf16(e2, e3);
            }

        // row sum of the SAME bf16-rounded P (consistency with PV numerator)
        float rs = 0.f;
        #pragma unroll
        for (int t = 0; t < 2; ++t)
            #pragma unroll
            for (int g = 0; g < 4; ++g)
                #pragma unroll
                for (int p = 0; p < 2; ++p) {
                    u32 w = pkw[t][g][p];
                    rs += bitf(w << 16) + bitf(w & 0xFFFF0000u);
                }
        rs += __shfl_xor(rs, 32, 64);
        l_run = l_run * alpha + rs;

        // rescale O by alpha (lane-local)
        #pragma unroll
        for (int v = 0; v < 4; ++v)
            #pragma unroll
            for (int e = 0; e < 16; ++e) O[v][e] *= alpha;

        // assemble PV B-fragments: symmetric lane^32 exchange of half the pairs
        s16x8 pb[4];
        #pragma unroll
        for (int c = 0; c < 4; ++c) {
            const int t = c >> 1, cl = c & 1;
            u32 snd0 = hi ? pkw[t][2 * cl][0] : pkw[t][2 * cl + 1][0];
            u32 snd1 = hi ? pkw[t][2 * cl][1] : pkw[t][2 * cl + 1][1];
            u32 rc0 = (u32)__shfl_xor((int)snd0, 32, 64);
            u32 rc1 = (u32)__shfl_xor((int)snd1, 32, 64);
            u32 w0 = hi ? rc0 : pkw[t][2 * cl][0];
            u32 w1 = hi ? rc1 : pkw[t][2 * cl][1];
            u32 w2 = hi ? pkw[t][2 * cl + 1][0] : rc0;
            u32 w3 = hi ? pkw[t][2 * cl + 1][1] : rc1;
            union { u32 w[4]; s16x8 v; } uu;
            uu.w[0] = w0; uu.w[1] = w1; uu.w[2] = w2; uu.w[3] = w3;
            pb[c] = uu.v;
        }

        // ---- PV (swapped): O^T += V^T * P^T,  32x32x16 ----
        const u16* Vb = Vd[kt & 1];
        __builtin_amdgcn_s_setprio(1);
        #pragma unroll
        for (int c = 0; c < 4; ++c) {
            #pragma unroll
            for (int v = 0; v < 4; ++v) {
                int rv = v * 32 + l31;
                int unit = (c * 2 + hi) ^ (l31 & 7);
                s16x8 af = *(const s16x8*)&Vb[rv * 64 + unit * 8];
                O[v] = __builtin_amdgcn_mfma_f32_32x32x16_bf16(af, pb[c], O[v], 0, 0, 0);
            }
        }
        __builtin_amdgcn_s_setprio(0);
    }

    // epilogue: normalize and store.  O[v] reg r ↦ vdim = v*32+(r&3)+8*(r>>2)+4*hi
    float linv = 1.0f / l_run;
    #pragma unroll
    for (int v = 0; v < 4; ++v) {
        #pragma unroll
        for (int g = 0; g < 4; ++g) {
            float o0 = O[v][g * 4 + 0] * linv;
            float o1 = O[v][g * 4 + 1] * linv;
            float o2 = O[v][g * 4 + 2] * linv;
            float o3 = O[v][g * 4 + 3] * linv;
            u32 w0 = (u32)f2bf(o0) | ((u32)f2bf(o1) << 16);
            u32 w1 = (u32)f2bf(o2) | ((u32)f2bf(o3) << 16);
            size_t off = (size_t)qrow * 2048 + h * 128 + v * 32 + g * 8 + hi * 4;
            *(u32x2*)&attnb[off] = (u32x2){w0, w1};
        }
    }
}

// ---------------------------------------------------------------------------
// Workspace layout (u16 elements): round-3 layout + vt at the end (122.7 MB).
// ---------------------------------------------------------------------------
extern "C" void kernel_launch(void* const* d_in, const int* in_sizes, int n_in,
                              void* d_out, int out_size, void* d_ws, size_t ws_size,
                              hipStream_t stream)
{
    const float* hidden = (const float*)d_in[0];
    const float* mask   = (const float*)d_in[1];
    const float* cosb   = (const float*)d_in[2];
    const float* sinb   = (const float*)d_in[3];
    const float* w_qd   = (const float*)d_in[4];
    const float* w_qu   = (const float*)d_in[5];
    const float* w_kvd  = (const float*)d_in[6];
    const float* w_kvu  = (const float*)d_in[7];
    const float* w_o    = (const float*)d_in[8];
    const float* qnw    = (const float*)d_in[9];
    const float* kvnw   = (const float*)d_in[10];
    float* out = (float*)d_out;

    u16* ws = (u16*)d_ws;
    u16* qbuf   = ws + 0;
    u16* wt_qd  = ws + 0;                       // dead before qbuf written
    u16* kvup   = ws + 12582912;
    u16* hid_bf = ws + 12582912;                // dead before kvup written
    u16* wt_kvd = ws + 20971520;                // dead before kvup written
    u16* attnb  = ws + 29360128;
    u16* qd     = ws + 29360128;                // dead before attnb written
    u16* wt_qu  = ws + 33554432;                // dead before attnb written
    u16* kvb    = ws + 37748736;
    u16* wt_o   = ws + 37748736;                // written after kvb dead (rope)
    u16* kvn    = ws + 40108032;
    u16* wt_kvu = ws + 42205184;
    u16* krot   = ws + 44302336;
    u16* vt     = ws + 44564480;                // 16,777,216 elems; end 122.7 MB

    // hidden f32 -> bf16
    {
        long long n2 = (long long)4096 * 2048 / 2;
        cvt_f32_bf16<<<(int)((n2 + 255) / 256), 256, 0, stream>>>(hidden, hid_bf, n2);
    }

    // q path
    transpose_f32_bf16<<<dim3(32, 64), 256, 0, stream>>>(w_qd, wt_qd, 2048, 1024);
    gemm128<u16><<<dim3(8, 32), 256, 0, stream>>>(hid_bf, wt_qd, qd, 4096, 1024, 2048);
    rmsnorm_kernel<<<4096, 256, 0, stream>>>(qd, qnw, qd, 1024, 1024, 1024);
    transpose_f32_bf16<<<dim3(96, 32), 256, 0, stream>>>(w_qu, wt_qu, 1024, 3072);
    gemm128<u16><<<dim3(24, 32), 256, 0, stream>>>(qd, wt_qu, qbuf, 4096, 3072, 1024);

    // kv path
    transpose_f32_bf16<<<dim3(18, 64), 256, 0, stream>>>(w_kvd, wt_kvd, 2048, 576);
    gemm_bf16<<<dim3(9, 64), 256, 0, stream>>>(hid_bf, wt_kvd, kvb, 4096, 576, 2048);
    rmsnorm_kernel<<<4096, 256, 0, stream>>>(kvb, kvnw, kvn, 512, 576, 512);
    transpose_f32_bf16<<<dim3(128, 16), 256, 0, stream>>>(w_kvu, wt_kvu, 512, 4096);
    gemm128<u16><<<dim3(32, 32), 256, 0, stream>>>(kvn, wt_kvu, kvup, 4096, 4096, 512);

    // V transpose for attention staging
    transpose_v<<<dim3(64, 4, 32), 256, 0, stream>>>(kvup, vt);

    // rope (q in-place + krot); then wt_o into space freed by kvb/kvn
    rope_kernel<<<4096, 256, 0, stream>>>(qbuf, kvb, krot, cosb, sinb);
    transpose_f32_bf16<<<dim3(64, 64), 256, 0, stream>>>(w_o, wt_o, 2048, 2048);

    // attention (MFMA flash v5: swapped 32x32, register-resident P)
    attn_mfma5<<<dim3(16, 16, 2), 256, 0, stream>>>(qbuf, kvup, krot, vt, mask, attnb);

    // output projection -> FLOAT32 output
    gemm128<float><<<dim3(16, 32), 256, 0, stream>>>(attnb, wt_o, out, 4096, 2048, 2048);
}

// Round 7
// 511.535 us; speedup vs baseline: 1.0514x; 1.0514x over previous
//
#include <hip/hip_runtime.h>
#include <hip/hip_bf16.h>

typedef unsigned short u16;
typedef unsigned int u32;
typedef short s16x8 __attribute__((ext_vector_type(8)));
typedef float f32x4 __attribute__((ext_vector_type(4)));
typedef float f32x2 __attribute__((ext_vector_type(2)));

__device__ __forceinline__ float bf2f(u16 u) {
    union { u32 i; float f; } v; v.i = ((u32)u) << 16; return v.f;
}
__device__ __forceinline__ u16 f2bf(float f) {
    union { float f; u32 i; } v; v.f = f;
    u32 i = v.i;
    u32 r = (i + 0x7FFFu + ((i >> 16) & 1u)) >> 16;   // round-to-nearest-even
    return (u16)r;
}

// async global->LDS, 16 B per lane: dest = lds_base + lane*16 (wave-uniform base)
__device__ __forceinline__ void gl2lds16(const u16* g, u16* l) {
    __builtin_amdgcn_global_load_lds(
        (const __attribute__((address_space(1))) u32*)g,
        (__attribute__((address_space(3))) u32*)l, 16, 0, 0);
}

// ---------------------------------------------------------------------------
// Convert f32 -> bf16, 2 elements/thread.
// ---------------------------------------------------------------------------
__global__ __launch_bounds__(256) void cvt_f32_bf16(
    const float* __restrict__ in, u16* __restrict__ out, long long n2)
{
    long long i = (long long)blockIdx.x * 256 + threadIdx.x;
    if (i < n2) {
        f32x2 v = *(const f32x2*)(in + i * 2);
        u32 p = (u32)f2bf(v[0]) | ((u32)f2bf(v[1]) << 16);
        *(u32*)(out + i * 2) = p;
    }
}

// ---------------------------------------------------------------------------
// Transpose + convert: f32 in[R][C] -> bf16 out[C][R].  R,C multiples of 32.
// ---------------------------------------------------------------------------
__global__ __launch_bounds__(256) void transpose_f32_bf16(
    const float* __restrict__ in, u16* __restrict__ out, int R, int C)
{
    __shared__ u16 t[32][33];
    int tx = threadIdx.x & 31, ty = threadIdx.x >> 5;
    int c0 = blockIdx.x * 32, r0 = blockIdx.y * 32;
    #pragma unroll
    for (int i = 0; i < 32; i += 8)
        t[ty + i][tx] = f2bf(in[(size_t)(r0 + ty + i) * C + c0 + tx]);
    __syncthreads();
    #pragma unroll
    for (int i = 0; i < 32; i += 8)
        out[(size_t)(c0 + ty + i) * R + r0 + tx] = t[tx][ty + i];
}

// ---------------------------------------------------------------------------
// V transpose: kvup V-half -> vt[b][h][v][s]  (bf16 -> bf16, 32x32 LDS tiles)
// grid = (64 s-tiles, 4 v-tiles, 32 bh), block = 256
// ---------------------------------------------------------------------------
__global__ __launch_bounds__(256) void transpose_v(
    const u16* __restrict__ kvup, u16* __restrict__ vt)
{
    __shared__ u16 t[32][33];
    int tx = threadIdx.x & 31, ty = threadIdx.x >> 5;
    int s0 = blockIdx.x * 32, v0 = blockIdx.y * 32;
    int b = blockIdx.z >> 4, h = blockIdx.z & 15;
    #pragma unroll
    for (int i = 0; i < 32; i += 8)
        t[ty + i][tx] = kvup[(size_t)(b * 2048 + s0 + ty + i) * 4096 + h * 256 + 128 + v0 + tx];
    __syncthreads();
    #pragma unroll
    for (int i = 0; i < 32; i += 8)
        vt[((size_t)(b * 16 + h) * 128 + v0 + ty + i) * 2048 + s0 + tx] = t[tx][ty + i];
}

// ---------------------------------------------------------------------------
// GEMM 64x64 tile (kept for kv_down: N=576 not /128).
// ---------------------------------------------------------------------------
__global__ __launch_bounds__(256) void gemm_bf16(
    const u16* __restrict__ A, const u16* __restrict__ Bt, u16* __restrict__ C,
    int M, int N, int K)
{
    __shared__ u16 As[64][40];
    __shared__ u16 Bs[64][40];

    const int tid  = threadIdx.x;
    const int wave = tid >> 6, lane = tid & 63;
    const int quad = lane >> 4, l16 = lane & 15;
    const int m0 = blockIdx.y * 64, n0 = blockIdx.x * 64;
    const int wm = (wave >> 1) * 32, wn = (wave & 1) * 32;

    const int srow = tid >> 2;
    const int koff = (tid & 3) * 8;

    f32x4 acc00 = {0.f,0.f,0.f,0.f};
    f32x4 acc01 = {0.f,0.f,0.f,0.f};
    f32x4 acc10 = {0.f,0.f,0.f,0.f};
    f32x4 acc11 = {0.f,0.f,0.f,0.f};

    for (int k0 = 0; k0 < K; k0 += 32) {
        *(s16x8*)&As[srow][koff] = *(const s16x8*)&A[(size_t)(m0 + srow) * K + k0 + koff];
        *(s16x8*)&Bs[srow][koff] = *(const s16x8*)&Bt[(size_t)(n0 + srow) * K + k0 + koff];
        __syncthreads();
        s16x8 a0 = *(const s16x8*)&As[wm + l16][quad * 8];
        s16x8 a1 = *(const s16x8*)&As[wm + 16 + l16][quad * 8];
        s16x8 b0 = *(const s16x8*)&Bs[wn + l16][quad * 8];
        s16x8 b1 = *(const s16x8*)&Bs[wn + 16 + l16][quad * 8];
        acc00 = __builtin_amdgcn_mfma_f32_16x16x32_bf16(a0, b0, acc00, 0, 0, 0);
        acc01 = __builtin_amdgcn_mfma_f32_16x16x32_bf16(a0, b1, acc01, 0, 0, 0);
        acc10 = __builtin_amdgcn_mfma_f32_16x16x32_bf16(a1, b0, acc10, 0, 0, 0);
        acc11 = __builtin_amdgcn_mfma_f32_16x16x32_bf16(a1, b1, acc11, 0, 0, 0);
        __syncthreads();
    }

    #pragma unroll
    for (int r = 0; r < 4; ++r) {
        int row0 = m0 + wm + quad * 4 + r;
        int col0 = n0 + wn + l16;
        C[(size_t)row0 * N + col0]             = f2bf(acc00[r]);
        C[(size_t)row0 * N + col0 + 16]        = f2bf(acc01[r]);
        C[(size_t)(row0 + 16) * N + col0]      = f2bf(acc10[r]);
        C[(size_t)(row0 + 16) * N + col0 + 16] = f2bf(acc11[r]);
    }
}

// ---------------------------------------------------------------------------
// GEMM 128x128 tile (m97 structure): 4 waves, each 64x64 via 4x4 of 16x16;
// BK=32; global_load_lds width-16 staging into unpadded row-major LDS.
// ---------------------------------------------------------------------------
template <typename OUT>
__global__ __launch_bounds__(256) void gemm128(
    const u16* __restrict__ A, const u16* __restrict__ Bt, OUT* __restrict__ C,
    int M, int N, int K)
{
    __shared__ u16 As[128 * 32];
    __shared__ u16 Bs[128 * 32];

    const int tid  = threadIdx.x;
    const int wave = tid >> 6, lane = tid & 63;
    const int quad = lane >> 4, l16 = lane & 15;
    const int m0 = blockIdx.y * 128, n0 = blockIdx.x * 128;
    const int wm = (wave >> 1) * 64, wn = (wave & 1) * 64;

    const int srow = lane >> 2, soct = (lane & 3) * 8;

    f32x4 acc[4][4];
    #pragma unroll
    for (int i = 0; i < 4; ++i)
        #pragma unroll
        for (int j = 0; j < 4; ++j) acc[i][j] = (f32x4){0.f,0.f,0.f,0.f};

    for (int k0 = 0; k0 < K; k0 += 32) {
        #pragma unroll
        for (int op = 0; op < 2; ++op) {
            int g = wave * 2 + op;
            gl2lds16(&A[(size_t)(m0 + g * 16 + srow) * K + k0 + soct], &As[g * 512]);
            gl2lds16(&Bt[(size_t)(n0 + g * 16 + srow) * K + k0 + soct], &Bs[g * 512]);
        }
        __syncthreads();
        s16x8 af[4], bf[4];
        #pragma unroll
        for (int i = 0; i < 4; ++i) {
            af[i] = *(const s16x8*)&As[(wm + i * 16 + l16) * 32 + quad * 8];
            bf[i] = *(const s16x8*)&Bs[(wn + i * 16 + l16) * 32 + quad * 8];
        }
        #pragma unroll
        for (int i = 0; i < 4; ++i)
            #pragma unroll
            for (int j = 0; j < 4; ++j)
                acc[i][j] = __builtin_amdgcn_mfma_f32_16x16x32_bf16(af[i], bf[j], acc[i][j], 0, 0, 0);
        __syncthreads();
    }

    #pragma unroll
    for (int i = 0; i < 4; ++i) {
        #pragma unroll
        for (int j = 0; j < 4; ++j) {
            #pragma unroll
            for (int r = 0; r < 4; ++r) {
                int row = m0 + wm + i * 16 + quad * 4 + r;
                int col = n0 + wn + j * 16 + l16;
                if constexpr (sizeof(OUT) == 2)
                    C[(size_t)row * N + col] = f2bf(acc[i][j][r]);
                else
                    C[(size_t)row * N + col] = acc[i][j][r];
            }
        }
    }
}

// ---------------------------------------------------------------------------
// RMSNorm rows: out = x * rsqrt(mean(x^2)+eps) * w  (x bf16, w f32, out bf16)
// ---------------------------------------------------------------------------
__global__ __launch_bounds__(256) void rmsnorm_kernel(
    const u16* __restrict__ in, const float* __restrict__ w, u16* __restrict__ out,
    int len, int istride, int ostride)
{
    const int row = blockIdx.x, tid = threadIdx.x;
    const u16* x = in + (size_t)row * istride;
    float ss = 0.f;
    for (int i = tid; i < len; i += 256) { float v = bf2f(x[i]); ss += v * v; }
    #pragma unroll
    for (int off = 32; off >= 1; off >>= 1) ss += __shfl_xor(ss, off, 64);
    __shared__ float wsum[4];
    if ((tid & 63) == 0) wsum[tid >> 6] = ss;
    __syncthreads();
    float tot = wsum[0] + wsum[1] + wsum[2] + wsum[3];
    float inv = 1.0f / sqrtf(tot / (float)len + 1e-6f);
    for (int i = tid; i < len; i += 256) {
        float v = bf2f(x[i]);
        out[(size_t)row * ostride + i] = f2bf(v * inv * w[i]);
    }
}

// ---------------------------------------------------------------------------
// RoPE: q rope halves (16 heads, in-place) + k_rope -> krot. cos/sin f32.
// ---------------------------------------------------------------------------
__global__ __launch_bounds__(256) void rope_kernel(
    u16* __restrict__ qb, const u16* __restrict__ kvb, u16* __restrict__ krot,
    const float* __restrict__ cosb, const float* __restrict__ sinb)
{
    const int row = blockIdx.x;
    const int s = row & 2047;
    const int lane = threadIdx.x & 63, wave = threadIdx.x >> 6;
    const float c  = cosb[s * 64 + lane];
    const float sn = sinb[s * 64 + lane];
    for (int seg = wave; seg < 17; seg += 4) {
        const u16* pin; u16* pout;
        if (seg < 16) { pout = qb + (size_t)row * 3072 + seg * 192 + 128; pin = pout; }
        else          { pin = kvb + (size_t)row * 576 + 512; pout = krot + (size_t)row * 64; }
        float x  = bf2f(pin[lane]);
        float xp = bf2f(pin[lane ^ 32]);
        float rot = (lane < 32) ? -xp : xp;
        pout[lane] = f2bf(x * c + rot * sn);
    }
}

// ---------------------------------------------------------------------------
// MFMA flash attention v9 = v4 (verified passing, 150 us) + defer-max (T13):
//  * common path: NO wave max-reduce, NO rescale.  __all(tm_local <= m+8)
//    performs the wave-wide bound check via the exec-mask compare — if every
//    lane's local max is bounded, the wave max is bounded.  P = exp2(S-m) is
//    then bounded by 2^8 (bf16-safe; numerator & denominator consistent).
//  * rare path (max grew > 8): full 6-shuffle wave max-reduce + alpha rescale
//    of O and l, exactly as v4.
//  Everything else is byte-identical to v4 (attn 150.0 us, total 515.2 us):
//  K reg-prefetch double-buffer, V async-DMA XOR-swizzled double buffer,
//  log2-domain softmax, hoisted mask loads, setprio around MFMA clusters.
// ---------------------------------------------------------------------------
__global__ __launch_bounds__(256, 2) void attn_mfma9(
    const u16* __restrict__ qb,     // [4096][3072]  (rope applied)
    const u16* __restrict__ kvup,   // [4096][4096]  (per head: 128 nope | 128 v)
    const u16* __restrict__ krot,   // [4096][64]
    const u16* __restrict__ vt,     // [2][16][128][2048]  V transposed
    const float* __restrict__ mask, // [2][2048]
    u16* __restrict__ attnb)        // [4096][2048]
{
    __shared__ u16 Ks[64 * 200];    // K tile, stride 200 u16 (400 B)
    __shared__ u16 Ps[128 * 72];    // P round-trip, wave-private rows
    __shared__ u16 Vd[2][128 * 64]; // V tile double buffer, linear + XOR swizzle

    const int tid  = threadIdx.x;
    const int wave = tid >> 6, lane = tid & 63;
    const int quad = lane >> 4, l16 = lane & 15;
    const int qt = blockIdx.x, h = blockIdx.y, b = blockIdx.z;
    const int row0 = b * 2048 + qt * 128;
    const int qw = wave * 16;
    const float scale2 = 0.10411610f;          // (1/sqrt(192)) * log2(e)
    const float l2e    = 1.4426950408889634f;
    const int swz = (l16 & 7) << 3;            // read-side V swizzle (u16 units)

    // all-ones bf16 fragment for row-sum MFMA
    s16x8 onesf;
    #pragma unroll
    for (int j = 0; j < 8; ++j) onesf[j] = (short)0x3F80;

    // Q fragments in registers: subtile s rows row0 + s*64 + qw + l16
    s16x8 qf[2][6];
    #pragma unroll
    for (int s = 0; s < 2; ++s)
        #pragma unroll
        for (int kc = 0; kc < 6; ++kc)
            qf[s][kc] = *(const s16x8*)&qb[(size_t)(row0 + s * 64 + qw + l16) * 3072
                                           + h * 192 + kc * 32 + quad * 8];

    // ---- K staging descriptors (6 x b128 per thread) ----
    const u16* pk[6]; int offk[6], stepk[6];
    #pragma unroll
    for (int i = 0; i < 6; ++i) {
        int idx = tid + i * 256;
        int r = idx / 24, c = (idx % 24) * 8;
        offk[i] = r * 200 + c;
        if (c < 128) { pk[i] = kvup + (size_t)(b * 2048 + r) * 4096 + h * 256 + c; stepk[i] = 64 * 4096; }
        else         { pk[i] = krot + (size_t)(b * 2048 + r) * 64 + (c - 128);     stepk[i] = 64 * 64;   }
    }

    // ---- V staging descriptors (4 x gl2lds per thread, pre-swizzled source) ----
    const u16* vtb = vt + (size_t)(b * 16 + h) * 128 * 2048;
    const u16* pv[4];
    #pragma unroll
    for (int i = 0; i < 4; ++i) {
        int widx = i * 4 + wave;                   // wave-uniform row group
        int r = widx * 8 + (lane >> 3);
        int u = (lane & 7) ^ (lane >> 3);          // source 16B unit, pre-swizzled
        pv[i] = vtb + (size_t)r * 2048 + u * 8;
    }

    // prologue: prefetch tile kt=0 (K into regs, V via DMA into Vd[0])
    s16x8 kreg[6];
    #pragma unroll
    for (int i = 0; i < 6; ++i) { kreg[i] = *(const s16x8*)pk[i]; pk[i] += stepk[i]; }
    #pragma unroll
    for (int i = 0; i < 4; ++i) {
        gl2lds16(pv[i], &Vd[0][(i * 4 + wave) * 512]);
        pv[i] += 64;
    }

    float m = -__builtin_inff();
    f32x4 l[2] = {(f32x4){0.f,0.f,0.f,0.f}, (f32x4){0.f,0.f,0.f,0.f}};
    f32x4 O[2][8];
    #pragma unroll
    for (int s = 0; s < 2; ++s)
        #pragma unroll
        for (int vi = 0; vi < 8; ++vi) O[s][vi] = (f32x4){0.f,0.f,0.f,0.f};

    for (int kt = 0; kt < 32; ++kt) {
        __syncthreads();   // A: prior iteration's Ks/Ps/Vd reads complete
        // write prefetched K tile (registers -> LDS); V already DMA'd
        #pragma unroll
        for (int i = 0; i < 6; ++i) *(s16x8*)&Ks[offk[i]] = kreg[i];
        __syncthreads();   // B: staging visible (drains K ds_writes + V DMA)

        // issue next tile's staging: latency hides under QK^T/softmax/PV
        if (kt < 31) {
            #pragma unroll
            for (int i = 0; i < 6; ++i) { kreg[i] = *(const s16x8*)pk[i]; pk[i] += stepk[i]; }
            #pragma unroll
            for (int i = 0; i < 4; ++i) {
                gl2lds16(pv[i], &Vd[(kt + 1) & 1][(i * 4 + wave) * 512]);
                pv[i] += 64;
            }
        }
        float mv4[4];
        #pragma unroll
        for (int ct = 0; ct < 4; ++ct)
            mv4[ct] = mask[b * 2048 + kt * 64 + ct * 16 + l16] * l2e;

        // ---- QK^T: both subtiles share Ks fragments ----
        f32x4 S[2][4];
        #pragma unroll
        for (int s = 0; s < 2; ++s)
            #pragma unroll
            for (int ct = 0; ct < 4; ++ct) S[s][ct] = (f32x4){0.f,0.f,0.f,0.f};
        __builtin_amdgcn_s_setprio(1);
        #pragma unroll
        for (int kc = 0; kc < 6; ++kc) {
            #pragma unroll
            for (int ct = 0; ct < 4; ++ct) {
                s16x8 bfr = *(const s16x8*)&Ks[(ct * 16 + l16) * 200 + kc * 32 + quad * 8];
                S[0][ct] = __builtin_amdgcn_mfma_f32_16x16x32_bf16(qf[0][kc], bfr, S[0][ct], 0, 0, 0);
                S[1][ct] = __builtin_amdgcn_mfma_f32_16x16x32_bf16(qf[1][kc], bfr, S[1][ct], 0, 0, 0);
            }
        }
        __builtin_amdgcn_s_setprio(0);

        // scale + mask (log2 domain)
        #pragma unroll
        for (int ct = 0; ct < 4; ++ct)
            #pragma unroll
            for (int s = 0; s < 2; ++s)
                #pragma unroll
                for (int r = 0; r < 4; ++r) S[s][ct][r] = S[s][ct][r] * scale2 + mv4[ct];

        // lane-local max of this wave's values
        float tm = S[0][0][0];
        #pragma unroll
        for (int s = 0; s < 2; ++s)
            #pragma unroll
            for (int ct = 0; ct < 4; ++ct)
                #pragma unroll
                for (int r = 0; r < 4; ++r) tm = fmaxf(tm, S[s][ct][r]);

        // defer-max (T13): __all checks the wave-wide bound on LOCAL maxima —
        // full shuffle-reduce + rescale only when the bound is exceeded.
        if (!__all(tm <= m + 8.0f)) {
            #pragma unroll
            for (int off = 1; off < 64; off <<= 1)
                tm = fmaxf(tm, __shfl_xor(tm, off, 64));
            float mn = fmaxf(m, tm);
            float alpha = exp2f(m - mn);
            m = mn;
            #pragma unroll
            for (int s = 0; s < 2; ++s) {
                l[s] *= alpha;
                #pragma unroll
                for (int vi = 0; vi < 8; ++vi) O[s][vi] *= alpha;
            }
        }

        // P = exp2(S - m) -> bf16 -> Ps (wave-private rows; same-wave RAW)
        #pragma unroll
        for (int s = 0; s < 2; ++s)
            #pragma unroll
            for (int ct = 0; ct < 4; ++ct)
                #pragma unroll
                for (int r = 0; r < 4; ++r)
                    Ps[(s * 64 + qw + quad * 4 + r) * 72 + ct * 16 + l16]
                        = f2bf(exp2f(S[s][ct][r] - m));

        // ---- PV + row-sum via ones-MFMA; Vd fragments shared across subtiles ----
        const u16* Vb = Vd[kt & 1];
        __builtin_amdgcn_s_setprio(1);
        #pragma unroll
        for (int kc = 0; kc < 2; ++kc) {
            s16x8 a0 = *(const s16x8*)&Ps[(qw + l16) * 72 + kc * 32 + quad * 8];
            s16x8 a1 = *(const s16x8*)&Ps[(64 + qw + l16) * 72 + kc * 32 + quad * 8];
            #pragma unroll
            for (int vi = 0; vi < 8; ++vi) {
                int rowv = vi * 16 + l16;
                int col  = kc * 32 + quad * 8;
                s16x8 bfr = *(const s16x8*)&Vb[rowv * 64 + (col ^ swz)];
                O[0][vi] = __builtin_amdgcn_mfma_f32_16x16x32_bf16(a0, bfr, O[0][vi], 0, 0, 0);
                O[1][vi] = __builtin_amdgcn_mfma_f32_16x16x32_bf16(a1, bfr, O[1][vi], 0, 0, 0);
            }
            l[0] = __builtin_amdgcn_mfma_f32_16x16x32_bf16(a0, onesf, l[0], 0, 0, 0);
            l[1] = __builtin_amdgcn_mfma_f32_16x16x32_bf16(a1, onesf, l[1], 0, 0, 0);
        }
        __builtin_amdgcn_s_setprio(0);
    }

    // epilogue: normalize and store
    #pragma unroll
    for (int s = 0; s < 2; ++s) {
        f32x4 linv;
        #pragma unroll
        for (int r = 0; r < 4; ++r) linv[r] = 1.0f / l[s][r];
        #pragma unroll
        for (int vi = 0; vi < 8; ++vi) {
            #pragma unroll
            for (int r = 0; r < 4; ++r) {
                int q_ = row0 + s * 64 + qw + quad * 4 + r;
                attnb[(size_t)q_ * 2048 + h * 128 + vi * 16 + l16] = f2bf(O[s][vi][r] * linv[r]);
            }
        }
    }
}

// ---------------------------------------------------------------------------
// Workspace layout (u16 elements): round-3 layout + vt at the end (122.7 MB).
// ---------------------------------------------------------------------------
extern "C" void kernel_launch(void* const* d_in, const int* in_sizes, int n_in,
                              void* d_out, int out_size, void* d_ws, size_t ws_size,
                              hipStream_t stream)
{
    const float* hidden = (const float*)d_in[0];
    const float* mask   = (const float*)d_in[1];
    const float* cosb   = (const float*)d_in[2];
    const float* sinb   = (const float*)d_in[3];
    const float* w_qd   = (const float*)d_in[4];
    const float* w_qu   = (const float*)d_in[5];
    const float* w_kvd  = (const float*)d_in[6];
    const float* w_kvu  = (const float*)d_in[7];
    const float* w_o    = (const float*)d_in[8];
    const float* qnw    = (const float*)d_in[9];
    const float* kvnw   = (const float*)d_in[10];
    float* out = (float*)d_out;

    u16* ws = (u16*)d_ws;
    u16* qbuf   = ws + 0;
    u16* wt_qd  = ws + 0;                       // dead before qbuf written
    u16* kvup   = ws + 12582912;
    u16* hid_bf = ws + 12582912;                // dead before kvup written
    u16* wt_kvd = ws + 20971520;                // dead before kvup written
    u16* attnb  = ws + 29360128;
    u16* qd     = ws + 29360128;                // dead before attnb written
    u16* wt_qu  = ws + 33554432;                // dead before attnb written
    u16* kvb    = ws + 37748736;
    u16* wt_o   = ws + 37748736;                // written after kvb dead (rope)
    u16* kvn    = ws + 40108032;
    u16* wt_kvu = ws + 42205184;
    u16* krot   = ws + 44302336;
    u16* vt     = ws + 44564480;                // 16,777,216 elems; end 122.7 MB

    // hidden f32 -> bf16
    {
        long long n2 = (long long)4096 * 2048 / 2;
        cvt_f32_bf16<<<(int)((n2 + 255) / 256), 256, 0, stream>>>(hidden, hid_bf, n2);
    }

    // q path
    transpose_f32_bf16<<<dim3(32, 64), 256, 0, stream>>>(w_qd, wt_qd, 2048, 1024);
    gemm128<u16><<<dim3(8, 32), 256, 0, stream>>>(hid_bf, wt_qd, qd, 4096, 1024, 2048);
    rmsnorm_kernel<<<4096, 256, 0, stream>>>(qd, qnw, qd, 1024, 1024, 1024);
    transpose_f32_bf16<<<dim3(96, 32), 256, 0, stream>>>(w_qu, wt_qu, 1024, 3072);
    gemm128<u16><<<dim3(24, 32), 256, 0, stream>>>(qd, wt_qu, qbuf, 4096, 3072, 1024);

    // kv path
    transpose_f32_bf16<<<dim3(18, 64), 256, 0, stream>>>(w_kvd, wt_kvd, 2048, 576);
    gemm_bf16<<<dim3(9, 64), 256, 0, stream>>>(hid_bf, wt_kvd, kvb, 4096, 576, 2048);
    rmsnorm_kernel<<<4096, 256, 0, stream>>>(kvb, kvnw, kvn, 512, 576, 512);
    transpose_f32_bf16<<<dim3(128, 16), 256, 0, stream>>>(w_kvu, wt_kvu, 512, 4096);
    gemm128<u16><<<dim3(32, 32), 256, 0, stream>>>(kvn, wt_kvu, kvup, 4096, 4096, 512);

    // V transpose for attention staging
    transpose_v<<<dim3(64, 4, 32), 256, 0, stream>>>(kvup, vt);

    // rope (q in-place + krot); then wt_o into space freed by kvb/kvn
    rope_kernel<<<4096, 256, 0, stream>>>(qbuf, kvb, krot, cosb, sinb);
    transpose_f32_bf16<<<dim3(64, 64), 256, 0, stream>>>(w_o, wt_o, 2048, 2048);

    // attention (MFMA flash v9: v4 + defer-max)
    attn_mfma9<<<dim3(16, 16, 2), 256, 0, stream>>>(qbuf, kvup, krot, vt, mask, attnb);

    // output projection -> FLOAT32 output
    gemm128<float><<<dim3(16, 32), 256, 0, stream>>>(attnb, wt_o, out, 4096, 2048, 2048);
}